// Round 1
// baseline (126.253 us; speedup 1.0000x reference)
//
#include <hip/hip_runtime.h>

typedef __attribute__((ext_vector_type(8))) short short8;
typedef __attribute__((ext_vector_type(4))) float f32x4;

__device__ __forceinline__ unsigned short f2b(float x) {
  union { float f; unsigned u; } v; v.f = x;
  unsigned r = v.u + 0x7fffu + ((v.u >> 16) & 1u);
  return (unsigned short)(r >> 16);
}

// ---- prep: transpose + bf16-convert weights into workspace ----
// W1T [512][128]: rows 0..255 = Wv^T; rows 256..511 = Wg^T with columns
// pre-permuted so gate channel for output c=h*64+d is at row 256+c.
// WoT [128][256] = Wo^T.  bg2[256] = permuted gate bias.
__global__ __launch_bounds__(256) void prep_kernel(
    const float* __restrict__ Wv, const float* __restrict__ Wg,
    const float* __restrict__ bgv, const float* __restrict__ Wo,
    unsigned short* __restrict__ W1T, unsigned short* __restrict__ WoT,
    float* __restrict__ bg2)
{
  int t = blockIdx.x * 256 + threadIdx.x;
  if (t < 512 * 128) {
    int c = t >> 7, e = t & 127;
    float val;
    if (c < 256) {
      val = Wv[e * 256 + c];
    } else {
      int cc = c - 256;                       // cc = h*64+d
      val = Wg[e * 256 + ((cc & 63) << 2) + (cc >> 6)];  // gate idx d*4+h
    }
    W1T[t] = f2b(val);
  } else if (t < 512 * 128 + 128 * 256) {
    int u = t - 512 * 128;
    int o = u >> 8, c = u & 255;
    WoT[u] = f2b(Wo[c * 128 + o]);
  } else if (t < 512 * 128 + 128 * 256 + 256) {
    int c = t - (512 * 128 + 128 * 256);
    bg2[c] = bgv[((c & 63) << 2) + (c >> 6)];
  }
}

// ---- fused: per 64-row tile: V/G GEMM -> sigmoid*V -> @Wo + bo ----
__global__ __launch_bounds__(256) void fused_kernel(
    const float* __restrict__ X,              // [65536][128] f32
    const unsigned short* __restrict__ W1T,   // [512][128] bf16
    const unsigned short* __restrict__ WoT,   // [128][256] bf16
    const float* __restrict__ bg2,            // [256]
    const float* __restrict__ bo,             // [128]
    float* __restrict__ Out)                  // [65536][128] f32
{
  __shared__ unsigned short Xs[64 * 128];     // bf16, XOR-swizzled rows
  __shared__ unsigned short Ys[64 * 256];     // bf16, XOR-swizzled rows

  const int tid  = threadIdx.x;
  const int lane = tid & 63;
  const int wave = tid >> 6;
  const int l15  = lane & 15;
  const int lhi  = lane >> 4;
  const long rowbase = (long)blockIdx.x * 64;

  // ---- stage X tile: 64x128 f32 (contiguous 32KB) -> bf16 LDS ----
  const float4* Xblk = reinterpret_cast<const float4*>(X + rowbase * 128);
  #pragma unroll
  for (int it = 0; it < 8; ++it) {
    int idx4 = it * 256 + tid;                // coalesced float4 index
    float4 f = Xblk[idx4];
    int e0  = idx4 * 4;
    int row = e0 >> 7;
    int col = e0 & 127;
    int sidx = (row * 128 + col) ^ ((row & 7) << 3);   // 16B-granular XOR swizzle
    ushort4 u;
    u.x = f2b(f.x); u.y = f2b(f.y); u.z = f2b(f.z); u.w = f2b(f.w);
    *reinterpret_cast<ushort4*>(&Xs[sidx]) = u;
  }
  __syncthreads();

  // ---- A-fragments (X) into registers: afrag[mt][ks] ----
  short8 afrag[4][4];
  #pragma unroll
  for (int mt = 0; mt < 4; ++mt) {
    int row = mt * 16 + l15;
    #pragma unroll
    for (int ks = 0; ks < 4; ++ks) {
      int sidx = (row * 128 + ks * 32 + lhi * 8) ^ ((row & 7) << 3);
      afrag[mt][ks] = *reinterpret_cast<const short8*>(&Xs[sidx]);
    }
  }

  const f32x4 vzero = {0.f, 0.f, 0.f, 0.f};

  // ---- stage 1: V and G for this wave's 64-col band, gate, write Ys ----
  #pragma unroll
  for (int t = 0; t < 4; ++t) {
    int c0 = (wave * 4 + t) * 16;
    const unsigned short* WVrow = W1T + (c0 + l15) * 128 + lhi * 8;
    const unsigned short* WGrow = WVrow + 256 * 128;
    f32x4 accV[4], accG[4];
    #pragma unroll
    for (int mt = 0; mt < 4; ++mt) { accV[mt] = vzero; accG[mt] = vzero; }
    #pragma unroll
    for (int ks = 0; ks < 4; ++ks) {
      short8 bV = *reinterpret_cast<const short8*>(WVrow + ks * 32);
      short8 bG = *reinterpret_cast<const short8*>(WGrow + ks * 32);
      #pragma unroll
      for (int mt = 0; mt < 4; ++mt) {
        accV[mt] = __builtin_amdgcn_mfma_f32_16x16x32_bf16(afrag[mt][ks], bV, accV[mt], 0, 0, 0);
        accG[mt] = __builtin_amdgcn_mfma_f32_16x16x32_bf16(afrag[mt][ks], bG, accG[mt], 0, 0, 0);
      }
    }
    float bgval = bg2[c0 + l15];
    #pragma unroll
    for (int mt = 0; mt < 4; ++mt) {
      #pragma unroll
      for (int r = 0; r < 4; ++r) {
        int row = mt * 16 + lhi * 4 + r;      // C/D layout: col=lane&15, row=(lane>>4)*4+r
        float z = accG[mt][r] + bgval;
        float g = 1.0f / (1.0f + __expf(-z));
        float y = g * accV[mt][r];
        int sidx = (row * 256 + c0 + l15) ^ ((row & 7) << 3);
        Ys[sidx] = f2b(y);
      }
    }
  }
  __syncthreads();

  // ---- stage 2: Out = Ys @ Wo + bo ----
  f32x4 acc2[2][4];
  #pragma unroll
  for (int nn = 0; nn < 2; ++nn)
    #pragma unroll
    for (int mt = 0; mt < 4; ++mt) acc2[nn][mt] = vzero;

  int o0 = wave * 16;                          // wave's output cols: o0.. and 64+o0..
  #pragma unroll
  for (int ks = 0; ks < 8; ++ks) {
    short8 b0 = *reinterpret_cast<const short8*>(WoT + (o0 + l15) * 256 + ks * 32 + lhi * 8);
    short8 b1 = *reinterpret_cast<const short8*>(WoT + (64 + o0 + l15) * 256 + ks * 32 + lhi * 8);
    #pragma unroll
    for (int mt = 0; mt < 4; ++mt) {
      int row = mt * 16 + l15;
      int sidx = (row * 256 + ks * 32 + lhi * 8) ^ ((row & 7) << 3);
      short8 a = *reinterpret_cast<const short8*>(&Ys[sidx]);
      acc2[0][mt] = __builtin_amdgcn_mfma_f32_16x16x32_bf16(a, b0, acc2[0][mt], 0, 0, 0);
      acc2[1][mt] = __builtin_amdgcn_mfma_f32_16x16x32_bf16(a, b1, acc2[1][mt], 0, 0, 0);
    }
  }
  #pragma unroll
  for (int nn = 0; nn < 2; ++nn) {
    int o = nn * 64 + o0 + l15;
    float bov = bo[o];
    #pragma unroll
    for (int mt = 0; mt < 4; ++mt) {
      #pragma unroll
      for (int r = 0; r < 4; ++r) {
        long row = rowbase + mt * 16 + lhi * 4 + r;
        Out[row * 128 + o] = acc2[nn][mt][r] + bov;
      }
    }
  }
}

extern "C" void kernel_launch(void* const* d_in, const int* in_sizes, int n_in,
                              void* d_out, int out_size, void* d_ws, size_t ws_size,
                              hipStream_t stream) {
  // inputs: 0 inter_edges, 1 ab_mask, 2 at_mask, 3 Wq, 4 Wk, 5 Wv, 6 Web,
  //         7 Wg, 8 bg, 9 Wo, 10 bo   (Wq/Wk/Web/masks mathematically unused)
  const float* X   = (const float*)d_in[0];
  const float* Wv  = (const float*)d_in[5];
  const float* Wg  = (const float*)d_in[7];
  const float* bg  = (const float*)d_in[8];
  const float* Wo  = (const float*)d_in[9];
  const float* bo  = (const float*)d_in[10];

  unsigned short* W1T = (unsigned short*)d_ws;            // 512*128 bf16
  unsigned short* WoT = W1T + 512 * 128;                  // 128*256 bf16
  float*          bg2 = (float*)(WoT + 128 * 256);        // 256 f32

  prep_kernel<<<385, 256, 0, stream>>>(Wv, Wg, bg, Wo, W1T, WoT, bg2);

  float* Out = (float*)d_out;
  fused_kernel<<<1024, 256, 0, stream>>>(X, W1T, WoT, bg2, bo, Out);
}